// Round 16
// baseline (256.489 us; speedup 1.0000x reference)
//
#include <hip/hip_runtime.h>
#include <hip/hip_bf16.h>

#define NEDGES 80000
#define NTRIP  640000
#define NQUAD  1280000

typedef __attribute__((ext_vector_type(8))) short short8;
typedef __attribute__((ext_vector_type(4))) float f32x4;
typedef __attribute__((ext_vector_type(2))) _Float16 half2v;
typedef __attribute__((ext_vector_type(8))) _Float16 half8v;

__device__ __forceinline__ unsigned short f2bf(float f) {
  __hip_bfloat16 h = __float2bfloat16(f);
  return reinterpret_cast<unsigned short&>(h);
}
__device__ __forceinline__ float bf2f(short s) {
  union { unsigned u; float f; } u;
  u.u = ((unsigned)(unsigned short)s) << 16;
  return u.f;
}
__device__ __forceinline__ float sSiLU(float x) {
  return x * (1.0f / 0.6f) / (1.0f + __expf(-x));
}

// ---------------- pack kernel: weights -> bf16, MFMA B-fragment order ----------
__device__ __forceinline__ void pack_one(const float* __restrict__ W,
                                         unsigned short* __restrict__ dst,
                                         int p, int NT, int Ksrc, int N) {
  int j = p & 7;
  int l = (p >> 3) & 63;
  int rest = p >> 9;
  int nt = rest % NT;
  int kb = rest / NT;
  int k = kb * 32 + ((l >> 4) << 3) + j;
  int n = nt * 16 + (l & 15);
  float v = (k < Ksrc) ? W[(size_t)k * N + n] : 0.0f;
  dst[p] = f2bf(v);
}

__global__ __launch_bounds__(256) void kpack(
    const float* __restrict__ Wd, const float* __restrict__ Wrbf,
    const float* __restrict__ Wdown, const float* __restrict__ Wbil,
    const float* __restrict__ Wupca, const float* __restrict__ Wupac,
    unsigned short* __restrict__ WdP, unsigned short* __restrict__ WrbfP,
    unsigned short* __restrict__ WdownP, unsigned short* __restrict__ WbilP,
    unsigned short* __restrict__ WupcaP, unsigned short* __restrict__ WupacP) {
  int idx = blockIdx.x * 256 + threadIdx.x;
  if (idx < 16384)        pack_one(Wd,    WdP,    idx,          8, 128,  128);
  else if (idx < 20480)   pack_one(Wrbf,  WrbfP,  idx - 16384,  8, 16,   128);
  else if (idx < 28672)   pack_one(Wdown, WdownP, idx - 20480,  4, 128,  64);
  else if (idx < 159744)  pack_one(Wbil,  WbilP,  idx - 28672,  4, 2048, 64);
  else if (idx < 167936)  pack_one(Wupca, WupcaP, idx - 159744, 8, 64,   128);
  else if (idx < 176128)  pack_one(Wupac, WupacP, idx - 167936, 8, 64,   128);
}

// ---------------- kernel A: x_down(bf16) = ss( (ss(m@Wd)*(rbf@Wrbf)) @ Wdown ) --
__global__ __launch_bounds__(256) void kA(
    const float* __restrict__ m, const float* __restrict__ rbf,
    const unsigned short* __restrict__ WdP, const unsigned short* __restrict__ WrbfP,
    const unsigned short* __restrict__ WdownP, unsigned short* __restrict__ x_down) {
  __shared__ unsigned short h_lds[4][16][136];
  const int tid = threadIdx.x;
  const int w = tid >> 6, l = tid & 63;
  const int el = l & 15, g = l >> 4;
  const int ebase = blockIdx.x * 64 + w * 16;

  short8 am[4];
  {
    const float* mrow = m + (size_t)(ebase + el) * 128 + g * 8;
#pragma unroll
    for (int kb = 0; kb < 4; ++kb) {
      const f32x4 lo = *reinterpret_cast<const f32x4*>(mrow + kb * 32);
      const f32x4 hi = *reinterpret_cast<const f32x4*>(mrow + kb * 32 + 4);
      short8 a;
      a[0] = f2bf(lo[0]); a[1] = f2bf(lo[1]); a[2] = f2bf(lo[2]); a[3] = f2bf(lo[3]);
      a[4] = f2bf(hi[0]); a[5] = f2bf(hi[1]); a[6] = f2bf(hi[2]); a[7] = f2bf(hi[3]);
      am[kb] = a;
    }
  }
  short8 ar;
  {
    const float* rrow = rbf + (size_t)(ebase + el) * 16 + (g & 1) * 8;
    const f32x4 lo = *reinterpret_cast<const f32x4*>(rrow);
    const f32x4 hi = *reinterpret_cast<const f32x4*>(rrow + 4);
    ar[0] = f2bf(lo[0]); ar[1] = f2bf(lo[1]); ar[2] = f2bf(lo[2]); ar[3] = f2bf(lo[3]);
    ar[4] = f2bf(hi[0]); ar[5] = f2bf(hi[1]); ar[6] = f2bf(hi[2]); ar[7] = f2bf(hi[3]);
  }

  f32x4 acc1[8], acc2[8];
  const f32x4 z = {0.f, 0.f, 0.f, 0.f};
#pragma unroll
  for (int nt = 0; nt < 8; ++nt) { acc1[nt] = z; acc2[nt] = z; }

#pragma unroll
  for (int kb = 0; kb < 4; ++kb) {
#pragma unroll
    for (int nt = 0; nt < 8; ++nt) {
      short8 b = *reinterpret_cast<const short8*>(WdP + (((kb * 8 + nt) * 64 + l) << 3));
      acc1[nt] = __builtin_amdgcn_mfma_f32_16x16x32_bf16(am[kb], b, acc1[nt], 0, 0, 0);
    }
  }
#pragma unroll
  for (int nt = 0; nt < 8; ++nt) {
    short8 b = *reinterpret_cast<const short8*>(WrbfP + ((nt * 64 + l) << 3));
    acc2[nt] = __builtin_amdgcn_mfma_f32_16x16x32_bf16(ar, b, acc2[nt], 0, 0, 0);
  }

#pragma unroll
  for (int nt = 0; nt < 8; ++nt)
#pragma unroll
    for (int r = 0; r < 4; ++r) {
      float h = sSiLU(acc1[nt][r]) * acc2[nt][r];
      h_lds[w][g * 4 + r][nt * 16 + el] = f2bf(h);
    }
  __syncthreads();

  f32x4 acc3[4];
#pragma unroll
  for (int nt = 0; nt < 4; ++nt) acc3[nt] = z;
#pragma unroll
  for (int kb = 0; kb < 4; ++kb) {
    short8 a = *reinterpret_cast<const short8*>(&h_lds[w][el][kb * 32 + g * 8]);
#pragma unroll
    for (int nt = 0; nt < 4; ++nt) {
      short8 b = *reinterpret_cast<const short8*>(WdownP + (((kb * 4 + nt) * 64 + l) << 3));
      acc3[nt] = __builtin_amdgcn_mfma_f32_16x16x32_bf16(a, b, acc3[nt], 0, 0, 0);
    }
  }
#pragma unroll
  for (int nt = 0; nt < 4; ++nt)
#pragma unroll
    for (int r = 0; r < 4; ++r)
      x_down[(size_t)(ebase + g * 4 + r) * 64 + nt * 16 + el] = f2bf(sSiLU(acc3[nt][r]));
}

// ---------------- kernel G: y[t][c] = x_down[intm[t]][c] * (cbf[t] @ Wcbf)[c] ---
__global__ __launch_bounds__(256) void kG(
    const float* __restrict__ cbf, const int* __restrict__ intm,
    const unsigned short* __restrict__ x_down, const float* __restrict__ Wcbf,
    unsigned short* __restrict__ y) {
  __shared__ float cbf_lds[4][16][16];   // 4KB, wave-private slices
  const int tid = threadIdx.x;
  const int w = tid >> 6, c = tid & 63;
  const int wid = blockIdx.x * 4 + w;    // 10000 waves

  float wc[16];
#pragma unroll
  for (int r = 0; r < 16; ++r) wc[r] = Wcbf[r * 64 + c];

#pragma unroll
  for (int it = 0; it < 4; ++it) {
    const int t0 = (wid * 4 + it) * 16;  // 16 consecutive triplets

    const int ivv = intm[t0 + (c & 15)];                       // coalesced, dup x4
    const f32x4 cq = *reinterpret_cast<const f32x4*>(          // 1KB contiguous
        cbf + (size_t)(t0 + (c >> 2)) * 16 + (c & 3) * 4);
    *reinterpret_cast<f32x4*>(&cbf_lds[w][c >> 2][(c & 3) * 4]) = cq;

    int es[16];
#pragma unroll
    for (int k = 0; k < 16; ++k) es[k] = __builtin_amdgcn_readlane(ivv, k);

    unsigned short xr[16];
#pragma unroll
    for (int k = 0; k < 16; ++k) xr[k] = x_down[(size_t)es[k] * 64 + c];

#pragma unroll
    for (int j = 0; j < 16; ++j) {
      const f32x4* cr = reinterpret_cast<const f32x4*>(&cbf_lds[w][j][0]);
      const f32x4 q0 = cr[0], q1 = cr[1], q2 = cr[2], q3 = cr[3];  // broadcast
      float proj = 0.f;
#pragma unroll
      for (int r = 0; r < 4; ++r) {
        proj = fmaf(q0[r], wc[r], proj);
        proj = fmaf(q1[r], wc[4 + r], proj);
        proj = fmaf(q2[r], wc[8 + r], proj);
        proj = fmaf(q3[r], wc[12 + r], proj);
      }
      y[(size_t)(t0 + j) * 64 + c] = f2bf(bf2f((short)xr[j]) * proj);
    }
  }
}

// ---------------- kernel S2: sumk[e][c][8s] (f16) = sum_k sph[e][k][s]*y[abd] --
__global__ __launch_bounds__(256) void kS2(
    const float* __restrict__ sph, const int* __restrict__ abd,
    const unsigned short* __restrict__ y, unsigned short* __restrict__ sumk) {
  __shared__ float sph_lds[4][172];
  const int tid = threadIdx.x;
  const int w = tid >> 6, c = tid & 63;
  const int wid = blockIdx.x * 4 + w;    // 10000 waves

#pragma unroll
  for (int it = 0; it < 8; ++it) {
    const int e = wid * 8 + it;

    const int tvv = abd[(size_t)(c & 15) * NEDGES + e];   // 16 lines, dup x4
    if (c < 42)
      *reinterpret_cast<f32x4*>(&sph_lds[w][c * 4]) =
          *reinterpret_cast<const f32x4*>(sph + (size_t)e * 168 + c * 4);

    int te[16];
#pragma unroll
    for (int k = 0; k < 16; ++k) te[k] = __builtin_amdgcn_readlane(tvv, k);

    unsigned short yv[16];
#pragma unroll
    for (int k = 0; k < 16; ++k) yv[k] = y[(size_t)te[k] * 64 + c];  // 128B rows

    float sk[7] = {0.f, 0.f, 0.f, 0.f, 0.f, 0.f, 0.f};
#pragma unroll
    for (int k = 0; k < 16; ++k) {
      const float row = bf2f((short)yv[k]);
#pragma unroll
      for (int s = 0; s < 7; ++s) sk[s] = fmaf(sph_lds[w][k * 7 + s], row, sk[s]);
    }
    half8v sv;
#pragma unroll
    for (int s = 0; s < 7; ++s) sv[s] = (_Float16)sk[s];
    sv[7] = (_Float16)0.f;
    *reinterpret_cast<half8v*>(sumk + (size_t)e * 512 + c * 8) = sv;  // coalesced
  }
}

// ---------------- kernel S (fused fallback; bf16 sumk, pairs with kB2f) --------
__global__ __launch_bounds__(256) void kS(
    const float* __restrict__ cbf, const float* __restrict__ sph,
    const int* __restrict__ abd, const int* __restrict__ intm,
    const unsigned short* __restrict__ x_down, const float* __restrict__ Wcbf,
    unsigned short* __restrict__ sumk) {
  __shared__ float cbf_lds[4][16][16];
  __shared__ int   te_lds[4][16];
  __shared__ float sph_lds[4][172];
  const int tid = threadIdx.x;
  const int w = tid >> 6, c = tid & 63;
  const int e = blockIdx.x * 4 + w;

  const int tvv = abd[(size_t)(c & 15) * NEDGES + e];
  if (c < 42)
    *reinterpret_cast<f32x4*>(&sph_lds[w][c * 4]) =
        *reinterpret_cast<const f32x4*>(sph + (size_t)e * 168 + c * 4);
  const int ivv = intm[tvv];
  if (c < 16) te_lds[w][c] = tvv;

  float wc[16];
#pragma unroll
  for (int r = 0; r < 16; ++r) wc[r] = Wcbf[r * 64 + c];

  int es[16];
#pragma unroll
  for (int k = 0; k < 16; ++k) es[k] = __builtin_amdgcn_readlane(ivv, k);

  const int tq = te_lds[w][c >> 2];
  const f32x4 cq = *reinterpret_cast<const f32x4*>(cbf + (size_t)tq * 16 + (c & 3) * 4);

  unsigned short xr[16];
#pragma unroll
  for (int k = 0; k < 16; ++k) xr[k] = x_down[(size_t)es[k] * 64 + c];

  *reinterpret_cast<f32x4*>(&cbf_lds[w][c >> 2][(c & 3) * 4]) = cq;

  float sk[7] = {0.f, 0.f, 0.f, 0.f, 0.f, 0.f, 0.f};
#pragma unroll
  for (int k = 0; k < 16; ++k) {
    const f32x4* cr = reinterpret_cast<const f32x4*>(&cbf_lds[w][k][0]);
    const f32x4 q0 = cr[0], q1 = cr[1], q2 = cr[2], q3 = cr[3];
    float proj = 0.f;
#pragma unroll
    for (int r = 0; r < 4; ++r) {
      proj = fmaf(q0[r], wc[r], proj);
      proj = fmaf(q1[r], wc[4 + r], proj);
      proj = fmaf(q2[r], wc[8 + r], proj);
      proj = fmaf(q3[r], wc[12 + r], proj);
    }
    const float row = bf2f((short)xr[k]) * proj;
#pragma unroll
    for (int s = 0; s < 7; ++s) sk[s] = fmaf(sph_lds[w][k * 7 + s], row, sk[s]);
  }
  short8 sv;
#pragma unroll
  for (int s = 0; s < 7; ++s) sv[s] = (short)f2bf(sk[s]);
  sv[7] = 0;
  *reinterpret_cast<short8*>(sumk + (size_t)e * 512 + c * 8) = sv;
}

// ---------------- kernel B3: bilinear GEMM, split-K=4, fdot2 t-build -----------
// Split-K 2->4: grid 2500->5000 blocks (19.5/CU) so residency is no longer
// grid-starved (R15: occupancy pinned at ~16 waves/CU with only 9.8 blocks/CU
// of supply). Partials in bf16 (4 slices fit y's slot); kU sums 4.
__global__ __launch_bounds__(256, 4) void kB3(
    const float* __restrict__ sbfW1, const unsigned short* __restrict__ sumk,
    const unsigned short* __restrict__ WbilP, unsigned short* __restrict__ xpartB) {
  __shared__ unsigned short stg[4][2][16][72];  // 18.4 KB
  const int tid = threadIdx.x;
  const int w = tid >> 6, l = tid & 63;
  const int el = l & 15, g = l >> 4;
  const int gw = blockIdx.x * 4 + w;
  const int eb = gw >> 2, kh = gw & 3;   // 5000 eb-tiles x 4 K-quarters
  const int ebase = eb * 16;
  const int sr = l >> 3, sq = l & 7;     // staging row (0..7), 16B-quad (0..7)

  // W1 -> 32 packed half2: w1h[j*4+p] covers s = {2p, 2p+1} (p=3: {6, pad0})
  half2v w1h[32];
  {
    float w1f[56];
    const f32x4* wp = reinterpret_cast<const f32x4*>(sbfW1 + (size_t)(ebase + el) * 224 + g * 56);
#pragma unroll
    for (int qq = 0; qq < 14; ++qq) {
      f32x4 v = wp[qq];
      w1f[qq * 4 + 0] = v[0]; w1f[qq * 4 + 1] = v[1];
      w1f[qq * 4 + 2] = v[2]; w1f[qq * 4 + 3] = v[3];
    }
#pragma unroll
    for (int j = 0; j < 8; ++j) {
#pragma unroll
      for (int p = 0; p < 3; ++p) {
        half2v h;
        h[0] = (_Float16)w1f[j * 7 + 2 * p];
        h[1] = (_Float16)w1f[j * 7 + 2 * p + 1];
        w1h[j * 4 + p] = h;
      }
      half2v h;
      h[0] = (_Float16)w1f[j * 7 + 6];
      h[1] = (_Float16)0.f;
      w1h[j * 4 + 3] = h;
    }
  }

  // base of this wave's kb-quarter within its 16 edge rows (16 kb x 8 shorts)
  const unsigned short* base = sumk + (size_t)ebase * 512 + kh * 128;
  short8 ld0 = *reinterpret_cast<const short8*>(base + (size_t)sr * 512 + sq * 8);
  short8 ld1 = *reinterpret_cast<const short8*>(base + (size_t)(sr + 8) * 512 + sq * 8);

  // 1-ahead B double-buffer
  short8 bn0, bn1, bn2, bn3;
  {
    const unsigned short* bp = WbilP + (((kh * 16 * 4) * 64 + l) << 3);
    bn0 = *reinterpret_cast<const short8*>(bp);
    bn1 = *reinterpret_cast<const short8*>(bp + (64 << 3));
    bn2 = *reinterpret_cast<const short8*>(bp + (128 << 3));
    bn3 = *reinterpret_cast<const short8*>(bp + (192 << 3));
  }

  const f32x4 z = {0.f, 0.f, 0.f, 0.f};
  f32x4 acc[4];
#pragma unroll
  for (int nt = 0; nt < 4; ++nt) acc[nt] = z;

#pragma unroll
  for (int s = 0; s < 2; ++s) {
    const int b = s & 1;
    *reinterpret_cast<short8*>(&stg[w][b][sr][sq * 8]) = ld0;
    *reinterpret_cast<short8*>(&stg[w][b][sr + 8][sq * 8]) = ld1;
    if (s < 1) {  // prefetch next stage (overlaps with this stage's compute)
      ld0 = *reinterpret_cast<const short8*>(base + (size_t)sr * 512 + (s + 1) * 64 + sq * 8);
      ld1 = *reinterpret_cast<const short8*>(base + (size_t)(sr + 8) * 512 + (s + 1) * 64 + sq * 8);
    }
#pragma unroll
    for (int kk = 0; kk < 8; ++kk) {
      const short8 bc0 = bn0, bc1 = bn1, bc2 = bn2, bc3 = bn3;
      if (!(s == 1 && kk == 7)) {
        const int kbn = kh * 16 + s * 8 + kk + 1;
        const unsigned short* bp = WbilP + (((kbn * 4) * 64 + l) << 3);
        bn0 = *reinterpret_cast<const short8*>(bp);
        bn1 = *reinterpret_cast<const short8*>(bp + (64 << 3));
        bn2 = *reinterpret_cast<const short8*>(bp + (128 << 3));
        bn3 = *reinterpret_cast<const short8*>(bp + (192 << 3));
      }

      const half8v skv = *reinterpret_cast<const half8v*>(&stg[w][b][el][kk * 8]);
      half2v sp0, sp1, sp2, sp3;
      sp0[0] = skv[0]; sp0[1] = skv[1];
      sp1[0] = skv[2]; sp1[1] = skv[3];
      sp2[0] = skv[4]; sp2[1] = skv[5];
      sp3[0] = skv[6]; sp3[1] = skv[7];

      short8 a;
#pragma unroll
      for (int j = 0; j < 8; ++j) {
        float t = 0.f;
        t = __builtin_amdgcn_fdot2(w1h[j * 4 + 0], sp0, t, false);
        t = __builtin_amdgcn_fdot2(w1h[j * 4 + 1], sp1, t, false);
        t = __builtin_amdgcn_fdot2(w1h[j * 4 + 2], sp2, t, false);
        t = __builtin_amdgcn_fdot2(w1h[j * 4 + 3], sp3, t, false);
        a[j] = (short)f2bf(t);
      }
      acc[0] = __builtin_amdgcn_mfma_f32_16x16x32_bf16(a, bc0, acc[0], 0, 0, 0);
      acc[1] = __builtin_amdgcn_mfma_f32_16x16x32_bf16(a, bc1, acc[1], 0, 0, 0);
      acc[2] = __builtin_amdgcn_mfma_f32_16x16x32_bf16(a, bc2, acc[2], 0, 0, 0);
      acc[3] = __builtin_amdgcn_mfma_f32_16x16x32_bf16(a, bc3, acc[3], 0, 0, 0);
    }
  }

  // bf16 partials: xpartB[kh][e][64]; C/D layout row=g*4+r, col=nt*16+el
  unsigned short* po = xpartB + (size_t)kh * (NEDGES * 64);
#pragma unroll
  for (int nt = 0; nt < 4; ++nt)
#pragma unroll
    for (int r = 0; r < 4; ++r)
      po[(size_t)(ebase + g * 4 + r) * 64 + nt * 16 + el] = f2bf(acc[nt][r]);
}

// ---------------- kernel U: out = (ss(x@Wca) + ss(x@Wac)[swap]) / sqrt(2) ------
// x = sum of 4 bf16 split-K partials (fused into A-frag build)
__global__ __launch_bounds__(256) void kU(
    const unsigned short* __restrict__ xpartB, const unsigned short* __restrict__ WupcaP,
    const unsigned short* __restrict__ WupacP, float* __restrict__ out) {
  const int tid = threadIdx.x;
  const int w = tid >> 6, l = tid & 63;
  const int el = l & 15, g = l >> 4;
  const int ebase = (blockIdx.x * 4 + w) * 16;

  const f32x4 z = {0.f, 0.f, 0.f, 0.f};
  f32x4 aca[8], acb[8];
#pragma unroll
  for (int nt = 0; nt < 8; ++nt) { aca[nt] = z; acb[nt] = z; }

#pragma unroll
  for (int kb = 0; kb < 2; ++kb) {
    short8 p0 = *reinterpret_cast<const short8*>(
        xpartB + 0ull * (NEDGES * 64) + (size_t)(ebase + el) * 64 + kb * 32 + g * 8);
    short8 p1 = *reinterpret_cast<const short8*>(
        xpartB + 1ull * (NEDGES * 64) + (size_t)(ebase + el) * 64 + kb * 32 + g * 8);
    short8 p2 = *reinterpret_cast<const short8*>(
        xpartB + 2ull * (NEDGES * 64) + (size_t)(ebase + el) * 64 + kb * 32 + g * 8);
    short8 p3 = *reinterpret_cast<const short8*>(
        xpartB + 3ull * (NEDGES * 64) + (size_t)(ebase + el) * 64 + kb * 32 + g * 8);
    short8 a;
#pragma unroll
    for (int j = 0; j < 8; ++j)
      a[j] = (short)f2bf(bf2f(p0[j]) + bf2f(p1[j]) + bf2f(p2[j]) + bf2f(p3[j]));
#pragma unroll
    for (int nt = 0; nt < 8; ++nt) {
      short8 w1 = *reinterpret_cast<const short8*>(WupcaP + (((kb * 8 + nt) * 64 + l) << 3));
      short8 w2 = *reinterpret_cast<const short8*>(WupacP + (((kb * 8 + nt) * 64 + l) << 3));
      aca[nt] = __builtin_amdgcn_mfma_f32_16x16x32_bf16(a, w1, aca[nt], 0, 0, 0);
      acb[nt] = __builtin_amdgcn_mfma_f32_16x16x32_bf16(a, w2, acb[nt], 0, 0, 0);
    }
  }
  const float inv = 0.70710678118654752f;
#pragma unroll
  for (int nt = 0; nt < 8; ++nt)
#pragma unroll
    for (int r = 0; r < 4; ++r) {
      float v = (sSiLU(aca[nt][r]) + sSiLU(acb[nt][r ^ 1])) * inv;
      out[(size_t)(ebase + g * 4 + r) * 128 + nt * 16 + el] = v;
    }
}

// ---------------- kernel B2f (fallback, R8 structure: LDS-staged, fused up) ----
__global__ __launch_bounds__(256) void kB2f(
    const float* __restrict__ sbfW1, const unsigned short* __restrict__ sumk,
    const unsigned short* __restrict__ WbilP, const unsigned short* __restrict__ WupcaP,
    const unsigned short* __restrict__ WupacP, float* __restrict__ out) {
  __shared__ unsigned short sk_lds[4][16][520];
  __shared__ unsigned short x_lds[4][16][72];
  const int tid = threadIdx.x;
  const int w = tid >> 6, l = tid & 63;
  const int el = l & 15, g = l >> 4;
  const int ebase = blockIdx.x * 64 + w * 16;

#pragma unroll
  for (int i = 0; i < 16; ++i) {
    const short8 v = *reinterpret_cast<const short8*>(sumk + (size_t)(ebase + i) * 512 + l * 8);
    *reinterpret_cast<short8*>(&sk_lds[w][i][l * 8]) = v;
  }

  float w1r[56];
  {
    const f32x4* wp = reinterpret_cast<const f32x4*>(sbfW1 + (size_t)(ebase + el) * 224 + g * 56);
#pragma unroll
    for (int qq = 0; qq < 14; ++qq) {
      f32x4 v = wp[qq];
      w1r[qq * 4 + 0] = v[0]; w1r[qq * 4 + 1] = v[1];
      w1r[qq * 4 + 2] = v[2]; w1r[qq * 4 + 3] = v[3];
    }
  }
  __syncthreads();

  const f32x4 z = {0.f, 0.f, 0.f, 0.f};
  f32x4 acc[4];
#pragma unroll
  for (int nt = 0; nt < 4; ++nt) acc[nt] = z;

#pragma unroll 4
  for (int kb = 0; kb < 64; ++kb) {
    const short8 skv = *reinterpret_cast<const short8*>(&sk_lds[w][el][kb * 8]);
    float skf[7];
#pragma unroll
    for (int s = 0; s < 7; ++s) skf[s] = bf2f(skv[s]);
    short8 a;
#pragma unroll
    for (int j = 0; j < 8; ++j) {
      float t = 0.f;
#pragma unroll
      for (int s = 0; s < 7; ++s) t = fmaf(w1r[j * 7 + s], skf[s], t);
      a[j] = (short)f2bf(t);
    }
    const unsigned short* bp = WbilP + (((kb * 4) * 64 + l) << 3);
#pragma unroll
    for (int nt = 0; nt < 4; ++nt) {
      short8 b = *reinterpret_cast<const short8*>(bp + ((nt * 64) << 3));
      acc[nt] = __builtin_amdgcn_mfma_f32_16x16x32_bf16(a, b, acc[nt], 0, 0, 0);
    }
  }

#pragma unroll
  for (int nt = 0; nt < 4; ++nt)
#pragma unroll
    for (int r = 0; r < 4; ++r)
      x_lds[w][g * 4 + r][nt * 16 + el] = f2bf(acc[nt][r]);
  __syncthreads();

  f32x4 aca[8], acb[8];
#pragma unroll
  for (int nt = 0; nt < 8; ++nt) { aca[nt] = z; acb[nt] = z; }
#pragma unroll
  for (int kb = 0; kb < 2; ++kb) {
    short8 a = *reinterpret_cast<const short8*>(&x_lds[w][el][kb * 32 + g * 8]);
#pragma unroll
    for (int nt = 0; nt < 8; ++nt) {
      short8 b1 = *reinterpret_cast<const short8*>(WupcaP + (((kb * 8 + nt) * 64 + l) << 3));
      short8 b2 = *reinterpret_cast<const short8*>(WupacP + (((kb * 8 + nt) * 64 + l) << 3));
      aca[nt] = __builtin_amdgcn_mfma_f32_16x16x32_bf16(a, b1, aca[nt], 0, 0, 0);
      acb[nt] = __builtin_amdgcn_mfma_f32_16x16x32_bf16(a, b2, acb[nt], 0, 0, 0);
    }
  }
  const float inv = 0.70710678118654752f;
#pragma unroll
  for (int nt = 0; nt < 8; ++nt)
#pragma unroll
    for (int r = 0; r < 4; ++r) {
      float v = (sSiLU(aca[nt][r]) + sSiLU(acb[nt][r ^ 1])) * inv;
      out[(size_t)(ebase + g * 4 + r) * 128 + nt * 16 + el] = v;
    }
}

// ---------------- launch ----------------
extern "C" void kernel_launch(void* const* d_in, const int* in_sizes, int n_in,
                              void* d_out, int out_size, void* d_ws, size_t ws_size,
                              hipStream_t stream) {
  const float* m     = (const float*)d_in[0];
  const float* rbf   = (const float*)d_in[1];
  const float* cbf   = (const float*)d_in[2];
  const float* sbfW1 = (const float*)d_in[3];
  const float* sph   = (const float*)d_in[4];
  const int* intm = (const int*)d_in[8];
  const int* abd  = (const int*)d_in[9];
  const float* Wd    = (const float*)d_in[10];
  const float* Wrbf  = (const float*)d_in[11];
  const float* Wcbf  = (const float*)d_in[12];
  const float* Wdown = (const float*)d_in[13];
  const float* Wbil  = (const float*)d_in[14];
  const float* Wupca = (const float*)d_in[15];
  const float* Wupac = (const float*)d_in[16];

  char* ws = (char*)d_ws;
  unsigned short* WdP    = (unsigned short*)(ws + 0);
  unsigned short* WrbfP  = (unsigned short*)(ws + 32768);
  unsigned short* WdownP = (unsigned short*)(ws + 40960);
  unsigned short* WbilP  = (unsigned short*)(ws + 57344);
  unsigned short* WupcaP = (unsigned short*)(ws + 319488);
  unsigned short* WupacP = (unsigned short*)(ws + 335872);
  unsigned short* x_down = (unsigned short*)(ws + 352256);             // 10,240,000 B
  unsigned short* y      = (unsigned short*)(ws + 352256 + 10240000);  // 81,920,000 B
  unsigned short* sumk   = (unsigned short*)(ws + 352256 + 10240000 + 81920000); // 81,920,000 B
  unsigned short* xpartB = y;              // split path: y dead after kS2 (41 MB used)
  unsigned short* sumk_f = y;              // fused path: sumk in y's slot
  const size_t needed_split = 352256ull + 10240000ull + 81920000ull + 81920000ull;

  kpack<<<688, 256, 0, stream>>>(Wd, Wrbf, Wdown, Wbil, Wupca, Wupac,
                                 WdP, WrbfP, WdownP, WbilP, WupcaP, WupacP);
  kA<<<1250, 256, 0, stream>>>(m, rbf, WdP, WrbfP, WdownP, x_down);
  if (ws_size >= needed_split) {
    kG<<<2500, 256, 0, stream>>>(cbf, intm, x_down, Wcbf, y);
    kS2<<<2500, 256, 0, stream>>>(sph, abd, y, sumk);
    kB3<<<5000, 256, 0, stream>>>(sbfW1, sumk, WbilP, xpartB);
    kU<<<1250, 256, 0, stream>>>(xpartB, WupcaP, WupacP, (float*)d_out);
  } else {
    kS<<<20000, 256, 0, stream>>>(cbf, sph, abd, intm, x_down, Wcbf, sumk_f);
    kB2f<<<1250, 256, 0, stream>>>(sbfW1, sumk_f, WbilP, WupcaP, WupacP, (float*)d_out);
  }
}

// Round 17
// 231.718 us; speedup vs baseline: 1.1069x; 1.1069x over previous
//
#include <hip/hip_runtime.h>
#include <hip/hip_bf16.h>

#define NEDGES 80000
#define NTRIP  640000
#define NQUAD  1280000

typedef __attribute__((ext_vector_type(8))) short short8;
typedef __attribute__((ext_vector_type(4))) float f32x4;
typedef __attribute__((ext_vector_type(2))) _Float16 half2v;
typedef __attribute__((ext_vector_type(8))) _Float16 half8v;

__device__ __forceinline__ unsigned short f2bf(float f) {
  __hip_bfloat16 h = __float2bfloat16(f);
  return reinterpret_cast<unsigned short&>(h);
}
__device__ __forceinline__ float bf2f(short s) {
  union { unsigned u; float f; } u;
  u.u = ((unsigned)(unsigned short)s) << 16;
  return u.f;
}
__device__ __forceinline__ float sSiLU(float x) {
  return x * (1.0f / 0.6f) / (1.0f + __expf(-x));
}

// ---------------- pack kernel: weights -> bf16, MFMA B-fragment order ----------
__device__ __forceinline__ void pack_one(const float* __restrict__ W,
                                         unsigned short* __restrict__ dst,
                                         int p, int NT, int Ksrc, int N) {
  int j = p & 7;
  int l = (p >> 3) & 63;
  int rest = p >> 9;
  int nt = rest % NT;
  int kb = rest / NT;
  int k = kb * 32 + ((l >> 4) << 3) + j;
  int n = nt * 16 + (l & 15);
  float v = (k < Ksrc) ? W[(size_t)k * N + n] : 0.0f;
  dst[p] = f2bf(v);
}

__global__ __launch_bounds__(256) void kpack(
    const float* __restrict__ Wd, const float* __restrict__ Wrbf,
    const float* __restrict__ Wdown, const float* __restrict__ Wbil,
    const float* __restrict__ Wupca, const float* __restrict__ Wupac,
    unsigned short* __restrict__ WdP, unsigned short* __restrict__ WrbfP,
    unsigned short* __restrict__ WdownP, unsigned short* __restrict__ WbilP,
    unsigned short* __restrict__ WupcaP, unsigned short* __restrict__ WupacP) {
  int idx = blockIdx.x * 256 + threadIdx.x;
  if (idx < 16384)        pack_one(Wd,    WdP,    idx,          8, 128,  128);
  else if (idx < 20480)   pack_one(Wrbf,  WrbfP,  idx - 16384,  8, 16,   128);
  else if (idx < 28672)   pack_one(Wdown, WdownP, idx - 20480,  4, 128,  64);
  else if (idx < 159744)  pack_one(Wbil,  WbilP,  idx - 28672,  4, 2048, 64);
  else if (idx < 167936)  pack_one(Wupca, WupcaP, idx - 159744, 8, 64,   128);
  else if (idx < 176128)  pack_one(Wupac, WupacP, idx - 167936, 8, 64,   128);
}

// ---------------- kernel A: x_down(bf16) = ss( (ss(m@Wd)*(rbf@Wrbf)) @ Wdown ) --
__global__ __launch_bounds__(256) void kA(
    const float* __restrict__ m, const float* __restrict__ rbf,
    const unsigned short* __restrict__ WdP, const unsigned short* __restrict__ WrbfP,
    const unsigned short* __restrict__ WdownP, unsigned short* __restrict__ x_down) {
  __shared__ unsigned short h_lds[4][16][136];
  const int tid = threadIdx.x;
  const int w = tid >> 6, l = tid & 63;
  const int el = l & 15, g = l >> 4;
  const int ebase = blockIdx.x * 64 + w * 16;

  short8 am[4];
  {
    const float* mrow = m + (size_t)(ebase + el) * 128 + g * 8;
#pragma unroll
    for (int kb = 0; kb < 4; ++kb) {
      const f32x4 lo = *reinterpret_cast<const f32x4*>(mrow + kb * 32);
      const f32x4 hi = *reinterpret_cast<const f32x4*>(mrow + kb * 32 + 4);
      short8 a;
      a[0] = f2bf(lo[0]); a[1] = f2bf(lo[1]); a[2] = f2bf(lo[2]); a[3] = f2bf(lo[3]);
      a[4] = f2bf(hi[0]); a[5] = f2bf(hi[1]); a[6] = f2bf(hi[2]); a[7] = f2bf(hi[3]);
      am[kb] = a;
    }
  }
  short8 ar;
  {
    const float* rrow = rbf + (size_t)(ebase + el) * 16 + (g & 1) * 8;
    const f32x4 lo = *reinterpret_cast<const f32x4*>(rrow);
    const f32x4 hi = *reinterpret_cast<const f32x4*>(rrow + 4);
    ar[0] = f2bf(lo[0]); ar[1] = f2bf(lo[1]); ar[2] = f2bf(lo[2]); ar[3] = f2bf(lo[3]);
    ar[4] = f2bf(hi[0]); ar[5] = f2bf(hi[1]); ar[6] = f2bf(hi[2]); ar[7] = f2bf(hi[3]);
  }

  f32x4 acc1[8], acc2[8];
  const f32x4 z = {0.f, 0.f, 0.f, 0.f};
#pragma unroll
  for (int nt = 0; nt < 8; ++nt) { acc1[nt] = z; acc2[nt] = z; }

#pragma unroll
  for (int kb = 0; kb < 4; ++kb) {
#pragma unroll
    for (int nt = 0; nt < 8; ++nt) {
      short8 b = *reinterpret_cast<const short8*>(WdP + (((kb * 8 + nt) * 64 + l) << 3));
      acc1[nt] = __builtin_amdgcn_mfma_f32_16x16x32_bf16(am[kb], b, acc1[nt], 0, 0, 0);
    }
  }
#pragma unroll
  for (int nt = 0; nt < 8; ++nt) {
    short8 b = *reinterpret_cast<const short8*>(WrbfP + ((nt * 64 + l) << 3));
    acc2[nt] = __builtin_amdgcn_mfma_f32_16x16x32_bf16(ar, b, acc2[nt], 0, 0, 0);
  }

#pragma unroll
  for (int nt = 0; nt < 8; ++nt)
#pragma unroll
    for (int r = 0; r < 4; ++r) {
      float h = sSiLU(acc1[nt][r]) * acc2[nt][r];
      h_lds[w][g * 4 + r][nt * 16 + el] = f2bf(h);
    }
  __syncthreads();

  f32x4 acc3[4];
#pragma unroll
  for (int nt = 0; nt < 4; ++nt) acc3[nt] = z;
#pragma unroll
  for (int kb = 0; kb < 4; ++kb) {
    short8 a = *reinterpret_cast<const short8*>(&h_lds[w][el][kb * 32 + g * 8]);
#pragma unroll
    for (int nt = 0; nt < 4; ++nt) {
      short8 b = *reinterpret_cast<const short8*>(WdownP + (((kb * 4 + nt) * 64 + l) << 3));
      acc3[nt] = __builtin_amdgcn_mfma_f32_16x16x32_bf16(a, b, acc3[nt], 0, 0, 0);
    }
  }
#pragma unroll
  for (int nt = 0; nt < 4; ++nt)
#pragma unroll
    for (int r = 0; r < 4; ++r)
      x_down[(size_t)(ebase + g * 4 + r) * 64 + nt * 16 + el] = f2bf(sSiLU(acc3[nt][r]));
}

// ---------------- kernel G: y[t][c] = x_down[intm[t]][c] * (cbf[t] @ Wcbf)[c] ---
__global__ __launch_bounds__(256) void kG(
    const float* __restrict__ cbf, const int* __restrict__ intm,
    const unsigned short* __restrict__ x_down, const float* __restrict__ Wcbf,
    unsigned short* __restrict__ y) {
  __shared__ float cbf_lds[4][16][16];   // 4KB, wave-private slices
  const int tid = threadIdx.x;
  const int w = tid >> 6, c = tid & 63;
  const int wid = blockIdx.x * 4 + w;    // 10000 waves

  float wc[16];
#pragma unroll
  for (int r = 0; r < 16; ++r) wc[r] = Wcbf[r * 64 + c];

#pragma unroll
  for (int it = 0; it < 4; ++it) {
    const int t0 = (wid * 4 + it) * 16;  // 16 consecutive triplets

    const int ivv = intm[t0 + (c & 15)];                       // coalesced, dup x4
    const f32x4 cq = *reinterpret_cast<const f32x4*>(          // 1KB contiguous
        cbf + (size_t)(t0 + (c >> 2)) * 16 + (c & 3) * 4);
    *reinterpret_cast<f32x4*>(&cbf_lds[w][c >> 2][(c & 3) * 4]) = cq;

    int es[16];
#pragma unroll
    for (int k = 0; k < 16; ++k) es[k] = __builtin_amdgcn_readlane(ivv, k);

    unsigned short xr[16];
#pragma unroll
    for (int k = 0; k < 16; ++k) xr[k] = x_down[(size_t)es[k] * 64 + c];

#pragma unroll
    for (int j = 0; j < 16; ++j) {
      const f32x4* cr = reinterpret_cast<const f32x4*>(&cbf_lds[w][j][0]);
      const f32x4 q0 = cr[0], q1 = cr[1], q2 = cr[2], q3 = cr[3];  // broadcast
      float proj = 0.f;
#pragma unroll
      for (int r = 0; r < 4; ++r) {
        proj = fmaf(q0[r], wc[r], proj);
        proj = fmaf(q1[r], wc[4 + r], proj);
        proj = fmaf(q2[r], wc[8 + r], proj);
        proj = fmaf(q3[r], wc[12 + r], proj);
      }
      y[(size_t)(t0 + j) * 64 + c] = f2bf(bf2f((short)xr[j]) * proj);
    }
  }
}

// ---------------- kernel S2: sumk[e][c][8s] (f16) = sum_k sph[e][k][s]*y[abd] --
__global__ __launch_bounds__(256) void kS2(
    const float* __restrict__ sph, const int* __restrict__ abd,
    const unsigned short* __restrict__ y, unsigned short* __restrict__ sumk) {
  __shared__ float sph_lds[4][172];
  const int tid = threadIdx.x;
  const int w = tid >> 6, c = tid & 63;
  const int wid = blockIdx.x * 4 + w;    // 10000 waves

#pragma unroll
  for (int it = 0; it < 8; ++it) {
    const int e = wid * 8 + it;

    const int tvv = abd[(size_t)(c & 15) * NEDGES + e];   // 16 lines, dup x4
    if (c < 42)
      *reinterpret_cast<f32x4*>(&sph_lds[w][c * 4]) =
          *reinterpret_cast<const f32x4*>(sph + (size_t)e * 168 + c * 4);

    int te[16];
#pragma unroll
    for (int k = 0; k < 16; ++k) te[k] = __builtin_amdgcn_readlane(tvv, k);

    unsigned short yv[16];
#pragma unroll
    for (int k = 0; k < 16; ++k) yv[k] = y[(size_t)te[k] * 64 + c];  // 128B rows

    float sk[7] = {0.f, 0.f, 0.f, 0.f, 0.f, 0.f, 0.f};
#pragma unroll
    for (int k = 0; k < 16; ++k) {
      const float row = bf2f((short)yv[k]);
#pragma unroll
      for (int s = 0; s < 7; ++s) sk[s] = fmaf(sph_lds[w][k * 7 + s], row, sk[s]);
    }
    half8v sv;
#pragma unroll
    for (int s = 0; s < 7; ++s) sv[s] = (_Float16)sk[s];
    sv[7] = (_Float16)0.f;
    *reinterpret_cast<half8v*>(sumk + (size_t)e * 512 + c * 8) = sv;  // coalesced
  }
}

// ---------------- kernel S (fused fallback; bf16 sumk, pairs with kB2f) --------
__global__ __launch_bounds__(256) void kS(
    const float* __restrict__ cbf, const float* __restrict__ sph,
    const int* __restrict__ abd, const int* __restrict__ intm,
    const unsigned short* __restrict__ x_down, const float* __restrict__ Wcbf,
    unsigned short* __restrict__ sumk) {
  __shared__ float cbf_lds[4][16][16];
  __shared__ int   te_lds[4][16];
  __shared__ float sph_lds[4][172];
  const int tid = threadIdx.x;
  const int w = tid >> 6, c = tid & 63;
  const int e = blockIdx.x * 4 + w;

  const int tvv = abd[(size_t)(c & 15) * NEDGES + e];
  if (c < 42)
    *reinterpret_cast<f32x4*>(&sph_lds[w][c * 4]) =
        *reinterpret_cast<const f32x4*>(sph + (size_t)e * 168 + c * 4);
  const int ivv = intm[tvv];
  if (c < 16) te_lds[w][c] = tvv;

  float wc[16];
#pragma unroll
  for (int r = 0; r < 16; ++r) wc[r] = Wcbf[r * 64 + c];

  int es[16];
#pragma unroll
  for (int k = 0; k < 16; ++k) es[k] = __builtin_amdgcn_readlane(ivv, k);

  const int tq = te_lds[w][c >> 2];
  const f32x4 cq = *reinterpret_cast<const f32x4*>(cbf + (size_t)tq * 16 + (c & 3) * 4);

  unsigned short xr[16];
#pragma unroll
  for (int k = 0; k < 16; ++k) xr[k] = x_down[(size_t)es[k] * 64 + c];

  *reinterpret_cast<f32x4*>(&cbf_lds[w][c >> 2][(c & 3) * 4]) = cq;

  float sk[7] = {0.f, 0.f, 0.f, 0.f, 0.f, 0.f, 0.f};
#pragma unroll
  for (int k = 0; k < 16; ++k) {
    const f32x4* cr = reinterpret_cast<const f32x4*>(&cbf_lds[w][k][0]);
    const f32x4 q0 = cr[0], q1 = cr[1], q2 = cr[2], q3 = cr[3];
    float proj = 0.f;
#pragma unroll
    for (int r = 0; r < 4; ++r) {
      proj = fmaf(q0[r], wc[r], proj);
      proj = fmaf(q1[r], wc[4 + r], proj);
      proj = fmaf(q2[r], wc[8 + r], proj);
      proj = fmaf(q3[r], wc[12 + r], proj);
    }
    const float row = bf2f((short)xr[k]) * proj;
#pragma unroll
    for (int s = 0; s < 7; ++s) sk[s] = fmaf(sph_lds[w][k * 7 + s], row, sk[s]);
  }
  short8 sv;
#pragma unroll
  for (int s = 0; s < 7; ++s) sv[s] = (short)f2bf(sk[s]);
  sv[7] = 0;
  *reinterpret_cast<short8*>(sumk + (size_t)e * 512 + c * 8) = sv;
}

// ---------------- kernel BU: bilinear GEMM (split-K=2) + fused up-projection ---
// R15 kB3 body (103 us proven) + the split-K reduction and up-projection done
// in-block: waves (w, w+1) hold the two kh-halves of the same eb-tile, exchange
// bf16 partials via LDS, then each wave up-projects nt range [kh*4, kh*4+4)
// (both Wupca and Wupac so the e^1 swap stays wave-local). Eliminates kU and
// the 82 MB xpart global round-trip.
__global__ __launch_bounds__(256, 4) void kBU(
    const float* __restrict__ sbfW1, const unsigned short* __restrict__ sumk,
    const unsigned short* __restrict__ WbilP, const unsigned short* __restrict__ WupcaP,
    const unsigned short* __restrict__ WupacP, float* __restrict__ out) {
  __shared__ unsigned short stg[4][2][16][72];  // 18.4 KB staging ring
  __shared__ unsigned short xl[4][16][72];      // 9.2 KB bf16 partial x
  const int tid = threadIdx.x;
  const int w = tid >> 6, l = tid & 63;
  const int el = l & 15, g = l >> 4;
  const int gw = blockIdx.x * 4 + w;
  const int eb = gw >> 1, kh = gw & 1;
  const int ebase = eb * 16;
  const int sr = l >> 3, sq = l & 7;    // staging row (0..7), 16B-quad (0..7)

  // W1 -> 32 packed half2: w1h[j*4+p] covers s = {2p, 2p+1} (p=3: {6, pad0})
  half2v w1h[32];
  {
    float w1f[56];
    const f32x4* wp = reinterpret_cast<const f32x4*>(sbfW1 + (size_t)(ebase + el) * 224 + g * 56);
#pragma unroll
    for (int qq = 0; qq < 14; ++qq) {
      f32x4 v = wp[qq];
      w1f[qq * 4 + 0] = v[0]; w1f[qq * 4 + 1] = v[1];
      w1f[qq * 4 + 2] = v[2]; w1f[qq * 4 + 3] = v[3];
    }
#pragma unroll
    for (int j = 0; j < 8; ++j) {
#pragma unroll
      for (int p = 0; p < 3; ++p) {
        half2v h;
        h[0] = (_Float16)w1f[j * 7 + 2 * p];
        h[1] = (_Float16)w1f[j * 7 + 2 * p + 1];
        w1h[j * 4 + p] = h;
      }
      half2v h;
      h[0] = (_Float16)w1f[j * 7 + 6];
      h[1] = (_Float16)0.f;
      w1h[j * 4 + 3] = h;
    }
  }

  // base of this wave's kb-half within its 16 edge rows
  const unsigned short* base = sumk + (size_t)ebase * 512 + kh * 256;
  short8 ld0 = *reinterpret_cast<const short8*>(base + (size_t)sr * 512 + sq * 8);
  short8 ld1 = *reinterpret_cast<const short8*>(base + (size_t)(sr + 8) * 512 + sq * 8);

  // 1-ahead B double-buffer
  short8 bn0, bn1, bn2, bn3;
  {
    const unsigned short* bp = WbilP + (((kh * 32 * 4) * 64 + l) << 3);
    bn0 = *reinterpret_cast<const short8*>(bp);
    bn1 = *reinterpret_cast<const short8*>(bp + (64 << 3));
    bn2 = *reinterpret_cast<const short8*>(bp + (128 << 3));
    bn3 = *reinterpret_cast<const short8*>(bp + (192 << 3));
  }

  const f32x4 z = {0.f, 0.f, 0.f, 0.f};
  f32x4 acc[4];
#pragma unroll
  for (int nt = 0; nt < 4; ++nt) acc[nt] = z;

#pragma unroll
  for (int s = 0; s < 4; ++s) {
    const int b = s & 1;
    *reinterpret_cast<short8*>(&stg[w][b][sr][sq * 8]) = ld0;
    *reinterpret_cast<short8*>(&stg[w][b][sr + 8][sq * 8]) = ld1;
    if (s < 3) {  // prefetch next stage (overlaps with this stage's compute)
      ld0 = *reinterpret_cast<const short8*>(base + (size_t)sr * 512 + (s + 1) * 64 + sq * 8);
      ld1 = *reinterpret_cast<const short8*>(base + (size_t)(sr + 8) * 512 + (s + 1) * 64 + sq * 8);
    }
#pragma unroll
    for (int kk = 0; kk < 8; ++kk) {
      const short8 bc0 = bn0, bc1 = bn1, bc2 = bn2, bc3 = bn3;
      if (!(s == 3 && kk == 7)) {
        const int kbn = kh * 32 + s * 8 + kk + 1;
        const unsigned short* bp = WbilP + (((kbn * 4) * 64 + l) << 3);
        bn0 = *reinterpret_cast<const short8*>(bp);
        bn1 = *reinterpret_cast<const short8*>(bp + (64 << 3));
        bn2 = *reinterpret_cast<const short8*>(bp + (128 << 3));
        bn3 = *reinterpret_cast<const short8*>(bp + (192 << 3));
      }

      const half8v skv = *reinterpret_cast<const half8v*>(&stg[w][b][el][kk * 8]);
      half2v sp0, sp1, sp2, sp3;
      sp0[0] = skv[0]; sp0[1] = skv[1];
      sp1[0] = skv[2]; sp1[1] = skv[3];
      sp2[0] = skv[4]; sp2[1] = skv[5];
      sp3[0] = skv[6]; sp3[1] = skv[7];

      short8 a;
#pragma unroll
      for (int j = 0; j < 8; ++j) {
        float t = 0.f;
        t = __builtin_amdgcn_fdot2(w1h[j * 4 + 0], sp0, t, false);
        t = __builtin_amdgcn_fdot2(w1h[j * 4 + 1], sp1, t, false);
        t = __builtin_amdgcn_fdot2(w1h[j * 4 + 2], sp2, t, false);
        t = __builtin_amdgcn_fdot2(w1h[j * 4 + 3], sp3, t, false);
        a[j] = (short)f2bf(t);
      }
      acc[0] = __builtin_amdgcn_mfma_f32_16x16x32_bf16(a, bc0, acc[0], 0, 0, 0);
      acc[1] = __builtin_amdgcn_mfma_f32_16x16x32_bf16(a, bc1, acc[1], 0, 0, 0);
      acc[2] = __builtin_amdgcn_mfma_f32_16x16x32_bf16(a, bc2, acc[2], 0, 0, 0);
      acc[3] = __builtin_amdgcn_mfma_f32_16x16x32_bf16(a, bc3, acc[3], 0, 0, 0);
    }
  }

  // partial x -> LDS (bf16), C/D layout row=g*4+r, col=nt*16+el
#pragma unroll
  for (int nt = 0; nt < 4; ++nt)
#pragma unroll
    for (int r = 0; r < 4; ++r)
      xl[w][g * 4 + r][nt * 16 + el] = f2bf(acc[nt][r]);
  __syncthreads();

  // ---- fused up-projection: x = xl[wa] + xl[wb]; this wave does nt in
  // [kh*4, kh*4+4) for its own eb (both Wupca and Wupac -> swap is local) ----
  const int wa = w & ~1, wb = wa + 1;
  f32x4 aca[4], acb[4];
#pragma unroll
  for (int nt = 0; nt < 4; ++nt) { aca[nt] = z; acb[nt] = z; }

#pragma unroll
  for (int kb = 0; kb < 2; ++kb) {
    const short8 p0 = *reinterpret_cast<const short8*>(&xl[wa][el][kb * 32 + g * 8]);
    const short8 p1 = *reinterpret_cast<const short8*>(&xl[wb][el][kb * 32 + g * 8]);
    short8 a;
#pragma unroll
    for (int j = 0; j < 8; ++j)
      a[j] = (short)f2bf(bf2f(p0[j]) + bf2f(p1[j]));
#pragma unroll
    for (int nt = 0; nt < 4; ++nt) {
      const int ntg = kh * 4 + nt;
      short8 b1 = *reinterpret_cast<const short8*>(WupcaP + (((kb * 8 + ntg) * 64 + l) << 3));
      short8 b2 = *reinterpret_cast<const short8*>(WupacP + (((kb * 8 + ntg) * 64 + l) << 3));
      aca[nt] = __builtin_amdgcn_mfma_f32_16x16x32_bf16(a, b1, aca[nt], 0, 0, 0);
      acb[nt] = __builtin_amdgcn_mfma_f32_16x16x32_bf16(a, b2, acb[nt], 0, 0, 0);
    }
  }
  const float inv = 0.70710678118654752f;
#pragma unroll
  for (int nt = 0; nt < 4; ++nt)
#pragma unroll
    for (int r = 0; r < 4; ++r) {
      const int ntg = kh * 4 + nt;
      float v = (sSiLU(aca[nt][r]) + sSiLU(acb[nt][r ^ 1])) * inv;
      out[(size_t)(ebase + g * 4 + r) * 128 + ntg * 16 + el] = v;
    }
}

// ---------------- kernel B2f (fallback, R8 structure: LDS-staged, fused up) ----
__global__ __launch_bounds__(256) void kB2f(
    const float* __restrict__ sbfW1, const unsigned short* __restrict__ sumk,
    const unsigned short* __restrict__ WbilP, const unsigned short* __restrict__ WupcaP,
    const unsigned short* __restrict__ WupacP, float* __restrict__ out) {
  __shared__ unsigned short sk_lds[4][16][520];
  __shared__ unsigned short x_lds[4][16][72];
  const int tid = threadIdx.x;
  const int w = tid >> 6, l = tid & 63;
  const int el = l & 15, g = l >> 4;
  const int ebase = blockIdx.x * 64 + w * 16;

#pragma unroll
  for (int i = 0; i < 16; ++i) {
    const short8 v = *reinterpret_cast<const short8*>(sumk + (size_t)(ebase + i) * 512 + l * 8);
    *reinterpret_cast<short8*>(&sk_lds[w][i][l * 8]) = v;
  }

  float w1r[56];
  {
    const f32x4* wp = reinterpret_cast<const f32x4*>(sbfW1 + (size_t)(ebase + el) * 224 + g * 56);
#pragma unroll
    for (int qq = 0; qq < 14; ++qq) {
      f32x4 v = wp[qq];
      w1r[qq * 4 + 0] = v[0]; w1r[qq * 4 + 1] = v[1];
      w1r[qq * 4 + 2] = v[2]; w1r[qq * 4 + 3] = v[3];
    }
  }
  __syncthreads();

  const f32x4 z = {0.f, 0.f, 0.f, 0.f};
  f32x4 acc[4];
#pragma unroll
  for (int nt = 0; nt < 4; ++nt) acc[nt] = z;

#pragma unroll 4
  for (int kb = 0; kb < 64; ++kb) {
    const short8 skv = *reinterpret_cast<const short8*>(&sk_lds[w][el][kb * 8]);
    float skf[7];
#pragma unroll
    for (int s = 0; s < 7; ++s) skf[s] = bf2f(skv[s]);
    short8 a;
#pragma unroll
    for (int j = 0; j < 8; ++j) {
      float t = 0.f;
#pragma unroll
      for (int s = 0; s < 7; ++s) t = fmaf(w1r[j * 7 + s], skf[s], t);
      a[j] = (short)f2bf(t);
    }
    const unsigned short* bp = WbilP + (((kb * 4) * 64 + l) << 3);
#pragma unroll
    for (int nt = 0; nt < 4; ++nt) {
      short8 b = *reinterpret_cast<const short8*>(bp + ((nt * 64) << 3));
      acc[nt] = __builtin_amdgcn_mfma_f32_16x16x32_bf16(a, b, acc[nt], 0, 0, 0);
    }
  }

#pragma unroll
  for (int nt = 0; nt < 4; ++nt)
#pragma unroll
    for (int r = 0; r < 4; ++r)
      x_lds[w][g * 4 + r][nt * 16 + el] = f2bf(acc[nt][r]);
  __syncthreads();

  f32x4 aca[8], acb[8];
#pragma unroll
  for (int nt = 0; nt < 8; ++nt) { aca[nt] = z; acb[nt] = z; }
#pragma unroll
  for (int kb = 0; kb < 2; ++kb) {
    short8 a = *reinterpret_cast<const short8*>(&x_lds[w][el][kb * 32 + g * 8]);
#pragma unroll
    for (int nt = 0; nt < 8; ++nt) {
      short8 b1 = *reinterpret_cast<const short8*>(WupcaP + (((kb * 8 + nt) * 64 + l) << 3));
      short8 b2 = *reinterpret_cast<const short8*>(WupacP + (((kb * 8 + nt) * 64 + l) << 3));
      aca[nt] = __builtin_amdgcn_mfma_f32_16x16x32_bf16(a, b1, aca[nt], 0, 0, 0);
      acb[nt] = __builtin_amdgcn_mfma_f32_16x16x32_bf16(a, b2, acb[nt], 0, 0, 0);
    }
  }
  const float inv = 0.70710678118654752f;
#pragma unroll
  for (int nt = 0; nt < 8; ++nt)
#pragma unroll
    for (int r = 0; r < 4; ++r) {
      float v = (sSiLU(aca[nt][r]) + sSiLU(acb[nt][r ^ 1])) * inv;
      out[(size_t)(ebase + g * 4 + r) * 128 + nt * 16 + el] = v;
    }
}

// ---------------- launch ----------------
extern "C" void kernel_launch(void* const* d_in, const int* in_sizes, int n_in,
                              void* d_out, int out_size, void* d_ws, size_t ws_size,
                              hipStream_t stream) {
  const float* m     = (const float*)d_in[0];
  const float* rbf   = (const float*)d_in[1];
  const float* cbf   = (const float*)d_in[2];
  const float* sbfW1 = (const float*)d_in[3];
  const float* sph   = (const float*)d_in[4];
  const int* intm = (const int*)d_in[8];
  const int* abd  = (const int*)d_in[9];
  const float* Wd    = (const float*)d_in[10];
  const float* Wrbf  = (const float*)d_in[11];
  const float* Wcbf  = (const float*)d_in[12];
  const float* Wdown = (const float*)d_in[13];
  const float* Wbil  = (const float*)d_in[14];
  const float* Wupca = (const float*)d_in[15];
  const float* Wupac = (const float*)d_in[16];

  char* ws = (char*)d_ws;
  unsigned short* WdP    = (unsigned short*)(ws + 0);
  unsigned short* WrbfP  = (unsigned short*)(ws + 32768);
  unsigned short* WdownP = (unsigned short*)(ws + 40960);
  unsigned short* WbilP  = (unsigned short*)(ws + 57344);
  unsigned short* WupcaP = (unsigned short*)(ws + 319488);
  unsigned short* WupacP = (unsigned short*)(ws + 335872);
  unsigned short* x_down = (unsigned short*)(ws + 352256);             // 10,240,000 B
  unsigned short* y      = (unsigned short*)(ws + 352256 + 10240000);  // 81,920,000 B
  unsigned short* sumk   = (unsigned short*)(ws + 352256 + 10240000 + 81920000); // 81,920,000 B
  unsigned short* sumk_f = y;              // fused path: sumk in y's slot
  const size_t needed_split = 352256ull + 10240000ull + 81920000ull + 81920000ull;

  kpack<<<688, 256, 0, stream>>>(Wd, Wrbf, Wdown, Wbil, Wupca, Wupac,
                                 WdP, WrbfP, WdownP, WbilP, WupcaP, WupacP);
  kA<<<1250, 256, 0, stream>>>(m, rbf, WdP, WrbfP, WdownP, x_down);
  if (ws_size >= needed_split) {
    kG<<<2500, 256, 0, stream>>>(cbf, intm, x_down, Wcbf, y);
    kS2<<<2500, 256, 0, stream>>>(sph, abd, y, sumk);
    kBU<<<2500, 256, 0, stream>>>(sbfW1, sumk, WbilP, WupcaP, WupacP, (float*)d_out);
  } else {
    kS<<<20000, 256, 0, stream>>>(cbf, sph, abd, intm, x_down, Wcbf, sumk_f);
    kB2f<<<1250, 256, 0, stream>>>(sbfW1, sumk_f, WbilP, WupcaP, WupacP, (float*)d_out);
  }
}